// Round 4
// baseline (340.441 us; speedup 1.0000x reference)
//
#include <hip/hip_runtime.h>

#define S_LEN 2048
#define DMODEL 1024
#define NHEADS 16
#define DKH 64

typedef __attribute__((ext_vector_type(8))) short bf16x8;
typedef __attribute__((ext_vector_type(4))) float f32x4;

#if __has_builtin(__builtin_amdgcn_exp2f)
#define EXP2F(x) __builtin_amdgcn_exp2f(x)
#define QSCALE (0.125f * 1.44269504f)   // scores pre-scaled to log2 domain
#else
#define EXP2F(x) __expf(x)
#define QSCALE 0.125f
#endif

static __device__ __forceinline__ short f2bf(float f) {
    unsigned b = __float_as_uint(f);
    b = (b + 0x7FFFu + ((b >> 16) & 1u)) >> 16;   // RNE
    return (short)b;
}

static __device__ __forceinline__ f32x4 mfma16(bf16x8 a, bf16x8 b, f32x4 c) {
    return __builtin_amdgcn_mfma_f32_16x16x32_bf16(a, b, c, 0, 0, 0);
}

static __device__ __forceinline__ void glds16(const short* g, short* l) {
    __builtin_amdgcn_global_load_lds(
        (const __attribute__((address_space(1))) void*)g,
        (__attribute__((address_space(3))) void*)l, 16, 0, 0);
}

// ---------------------------------------------------------------------------
// prep: fused fp32->bf16 convert (blocks 0..8191) + mask bit-pack (2048 blocks)
// ---------------------------------------------------------------------------
struct CvtArgs { const float* src[7]; short* dst[7]; };

__global__ __launch_bounds__(256) void prep(CvtArgs a, const int* __restrict__ mask,
                                            unsigned long long* __restrict__ mw) {
    if (blockIdx.x < 8192) {
        const size_t i8 = ((size_t)blockIdx.x * 256 + threadIdx.x) * 8;
        int seg; size_t off;
        if (i8 < ((size_t)12 << 20)) { seg = (int)(i8 >> 22); off = i8 & ((1u << 22) - 1); }
        else { size_t r = i8 - ((size_t)12 << 20); seg = 3 + (int)(r >> 20); off = r & ((1u << 20) - 1); }
        const float* s = a.src[seg] + off;
        float4 x0 = *(const float4*)s, x1 = *(const float4*)(s + 4);
        short o[8];
        o[0] = f2bf(x0.x); o[1] = f2bf(x0.y); o[2] = f2bf(x0.z); o[3] = f2bf(x0.w);
        o[4] = f2bf(x1.x); o[5] = f2bf(x1.y); o[6] = f2bf(x1.z); o[7] = f2bf(x1.w);
        *(uint4*)(a.dst[seg] + off) = *(uint4*)o;
    } else {
        const int wv = ((blockIdx.x - 8192) << 2) + (threadIdx.x >> 6);  // 0..8191
        const int lane = threadIdx.x & 63;
        const size_t base = (size_t)wv << 4;
        #pragma unroll 4
        for (int it = 0; it < 16; ++it) {
            const size_t w = base + it;
            const int m = mask[(w << 6) + lane];
            unsigned long long bal = __ballot(m != 0);
            if (lane == 0) mw[w] = bal;
        }
    }
}

// ---------------------------------------------------------------------------
// C = X @ W^T + bias (bf16, m97-style). MODE 0: bf16 headed [BH][S][DKH],
// value scaled by a.scale[z]; MODE 1: fp32 flat.
// ---------------------------------------------------------------------------
struct GemmArgs { const short* X[3]; const short* W[3]; const float* B[3];
                  void* C[3]; float scale[3]; };

template <int MODE>
__global__ __launch_bounds__(256) void gemm_bt(GemmArgs a) {
    __shared__ short Ah[128 * 32];
    __shared__ short Bh[128 * 32];
    const int z = blockIdx.z;
    const short* X = a.X[z];
    const short* W = a.W[z];
    const float* bias = a.B[z];
    const float scl = a.scale[z];

    const int t = threadIdx.x, wid = t >> 6, lane = t & 63;
    const int l15 = lane & 15, lq = lane >> 4;
    const int m0 = blockIdx.x << 7, n0 = blockIdx.y << 7;
    const int wm = (wid >> 1) << 6, wn = (wid & 1) << 6;

    const int kb = (lane & 3) ^ ((lane >> 3) & 3);
    const int r0 = (wid << 5) + (lane >> 2);
    const short* ag0 = X + (size_t)(m0 + r0) * 1024 + (kb << 3);
    const short* ag1 = ag0 + 16 * 1024;
    const short* bg0 = W + (size_t)(n0 + r0) * 1024 + (kb << 3);
    const short* bg1 = bg0 + 16 * 1024;
    short* lA0 = Ah + (wid << 5) * 32;
    short* lA1 = lA0 + 16 * 32;
    short* lB0 = Bh + (wid << 5) * 32;
    short* lB1 = lB0 + 16 * 32;

    const int fpos = (lq ^ ((l15 >> 1) & 3)) << 3;

    f32x4 acc[4][4] = {};

    for (int k0 = 0; k0 < 1024; k0 += 32) {
        __syncthreads();
        glds16(ag0, lA0); glds16(ag1, lA1);
        glds16(bg0, lB0); glds16(bg1, lB1);
        ag0 += 32; ag1 += 32; bg0 += 32; bg1 += 32;
        __syncthreads();

        bf16x8 af[4], bfr[4];
        #pragma unroll
        for (int i = 0; i < 4; ++i)
            af[i] = *(const bf16x8*)&Ah[(wm + i * 16 + l15) * 32 + fpos];
        #pragma unroll
        for (int j = 0; j < 4; ++j)
            bfr[j] = *(const bf16x8*)&Bh[(wn + j * 16 + l15) * 32 + fpos];
        #pragma unroll
        for (int i = 0; i < 4; ++i)
            #pragma unroll
            for (int j = 0; j < 4; ++j)
                acc[i][j] = mfma16(af[i], bfr[j], acc[i][j]);
    }

    #pragma unroll
    for (int j = 0; j < 4; ++j) {
        const int n = n0 + wn + j * 16 + l15;
        const float bn = bias[n];
        #pragma unroll
        for (int i = 0; i < 4; ++i) {
            const int mbase = m0 + wm + i * 16 + (lq << 2);
            #pragma unroll
            for (int r = 0; r < 4; ++r) {
                const float val = (acc[i][j][r] + bn) * scl;
                const int m = mbase + r;
                if (MODE == 0) {
                    const int b = m >> 11, s = m & 2047, h = n >> 6, d = n & 63;
                    ((short*)a.C[z])[((((size_t)(b * 16 + h)) << 11) + s) * 64 + d] = f2bf(val);
                } else {
                    ((float*)a.C[z])[((size_t)m << 10) + n] = val;
                }
            }
        }
    }
}

// ---------------------------------------------------------------------------
// ktr: kh [bh][s][64] -> kt [bh][64][2048], with within-64-group column
// permutation: kt[bh][d][s0+c] = kh[bh][s0 + jlog(c)][d], jlog(c)=((c&3)<<4)|(c>>2)
// (matches the phi packing of Ps so the PK MFMA k-sum is invariant).
// ---------------------------------------------------------------------------
__global__ __launch_bounds__(256) void ktr(const short* __restrict__ kh,
                                           short* __restrict__ kt) {
    __shared__ short Ls[64 * 68];
    const int t = threadIdx.x;
    const int s0 = blockIdx.x << 6, bh = blockIdx.y;
    {
        const int r = t >> 2, cb = (t & 3) << 4;
        const short* src = kh + ((size_t)bh * 2048 + s0 + r) * 64 + cb;
        *(uint4*)&Ls[r * 68 + cb + 0] = *(const uint4*)src;
        *(uint4*)&Ls[r * 68 + cb + 8] = *(const uint4*)(src + 8);
    }
    __syncthreads();
    const int d = t >> 2, c0 = (t & 3) << 4;
    short ov[16];
    #pragma unroll
    for (int e = 0; e < 16; ++e) {
        const int c = c0 + e;
        const int jl = ((c & 3) << 4) | (c >> 2);
        ov[e] = Ls[jl * 68 + d];
    }
    short* dst = kt + ((size_t)bh * 64 + d) * 2048 + s0 + c0;
    *(uint4*)(dst + 0) = *(uint4*)(ov + 0);
    *(uint4*)(dst + 8) = *(uint4*)(ov + 8);
}

// ---------------------------------------------------------------------------
// Barrier-free flash attention (reference K/V swap): S=Q@V^T (Q pre-scaled),
// mask, p=exp2(s), O = P@K / l. V,K frags loaded directly from global (K from
// permuted-transposed kt); only P round-trips LDS (wave-private band, no
// __syncthreads). Fixed-max softmax, deferred l-reduction.
// Block: 4 waves x 32 q-rows = 128 rows; grid (16, 32).
// ---------------------------------------------------------------------------
__global__ __launch_bounds__(256) void attn2(
    const short* __restrict__ Qh, const short* __restrict__ Vh,
    const short* __restrict__ Kt, const unsigned long long* __restrict__ MW,
    short* __restrict__ attr)
{
    constexpr int VP = 68;
    __shared__ short Ps[128 * VP];

    const int t = threadIdx.x, wid = t >> 6, lane = t & 63;
    const int l15 = lane & 15, lq = lane >> 4;
    const int bh = blockIdx.y, b = bh >> 4, h = bh & 15;
    const int q0 = blockIdx.x << 7;
    const int rowbase = q0 + (wid << 5);

    bf16x8 qf[2][2];
    #pragma unroll
    for (int mt = 0; mt < 2; ++mt) {
        const short* qp = Qh + ((size_t)bh * 2048 + rowbase + mt * 16 + l15) * 64 + (lq << 3);
        qf[mt][0] = *(const bf16x8*)qp;
        qf[mt][1] = *(const bf16x8*)(qp + 32);
    }

    const short* vgb = Vh + (size_t)bh * 2048 * 64;
    const short* kgb = Kt + (size_t)bh * 64 * 2048;
    const unsigned long long* mwp = MW + ((size_t)b * 2048 + rowbase) * 32;

    float rsum[2][4] = {};
    f32x4 O[2][4] = {};

    for (int jc = 0; jc < 32; ++jc) {
        const int j0 = jc << 6;

        // direct-global fragment loads (no LDS staging, no barrier)
        bf16x8 vf[4][2], kf[4][2];
        #pragma unroll
        for (int nt = 0; nt < 4; ++nt) {
            const short* vp = vgb + (size_t)(j0 + nt * 16 + l15) * 64 + (lq << 3);
            vf[nt][0] = *(const bf16x8*)vp;
            vf[nt][1] = *(const bf16x8*)(vp + 32);
            const short* kp = kgb + (size_t)(nt * 16 + l15) * 2048 + j0 + (lq << 3);
            kf[nt][0] = *(const bf16x8*)kp;
            kf[nt][1] = *(const bf16x8*)(kp + 32);
        }
        uint2 mwv[2][4];
        #pragma unroll
        for (int mt = 0; mt < 2; ++mt)
            #pragma unroll
            for (int r = 0; r < 4; ++r)
                mwv[mt][r] = *(const uint2*)&mwp[(size_t)(mt * 16 + (lq << 2) + r) * 32 + jc];

        #pragma unroll
        for (int mt = 0; mt < 2; ++mt) {
            f32x4 sc[4];
            #pragma unroll
            for (int nt = 0; nt < 4; ++nt) {
                f32x4 c = {};
                c = mfma16(qf[mt][0], vf[nt][0], c);
                c = mfma16(qf[mt][1], vf[nt][1], c);
                sc[nt] = c;
            }
            #pragma unroll
            for (int r = 0; r < 4; ++r) {
                unsigned px0 = 0, px1 = 0;
                #pragma unroll
                for (int nt = 0; nt < 4; ++nt) {
                    const unsigned sel = (nt < 2) ? mwv[mt][r].x : mwv[mt][r].y;
                    const unsigned bit = (sel >> (((nt & 1) << 4) + l15)) & 1u;
                    float p = EXP2F(sc[nt][r]);
                    p = bit ? p : 0.f;
                    const unsigned u = __float_as_uint(p) & 0xFFFF0000u;  // trunc bf16
                    rsum[mt][r] += __uint_as_float(u);
                    if (nt & 1) { if (nt >> 1) px1 |= u; else px0 |= u; }
                    else        { if (nt >> 1) px1 = u >> 16; else px0 = u >> 16; }
                }
                uint2 pw; pw.x = px0; pw.y = px1;
                *(uint2*)&Ps[((wid << 5) + mt * 16 + (lq << 2) + r) * VP + (l15 << 2)] = pw;
            }
        }

        // P frags (same-wave band; lgkm dependency only) + PK MFMAs
        bf16x8 pf[2][2];
        #pragma unroll
        for (int mt = 0; mt < 2; ++mt) {
            const short* pp = &Ps[((wid << 5) + mt * 16 + l15) * VP];
            pf[mt][0] = *(const bf16x8*)(pp + (lq << 3));
            pf[mt][1] = *(const bf16x8*)(pp + 32 + (lq << 3));
        }
        #pragma unroll
        for (int nt = 0; nt < 4; ++nt)
            #pragma unroll
            for (int mt = 0; mt < 2; ++mt) {
                O[mt][nt] = mfma16(pf[mt][0], kf[nt][0], O[mt][nt]);
                O[mt][nt] = mfma16(pf[mt][1], kf[nt][1], O[mt][nt]);
            }
    }

    #pragma unroll
    for (int mt = 0; mt < 2; ++mt)
        #pragma unroll
        for (int r = 0; r < 4; ++r) {
            float s = rsum[mt][r];
            #pragma unroll
            for (int d = 1; d < 16; d <<= 1)
                s += __shfl_xor(s, d, 64);
            const float inv = 1.f / s;
            const size_t row = (size_t)b * 2048 + rowbase + mt * 16 + (lq << 2) + r;
            #pragma unroll
            for (int nt = 0; nt < 4; ++nt)
                attr[row * 1024 + (h << 6) + nt * 16 + l15] = f2bf(O[mt][nt][r] * inv);
        }
}

// ---------------------------------------------------------------------------
extern "C" void kernel_launch(void* const* d_in, const int* in_sizes, int n_in,
                              void* d_out, int out_size, void* d_ws, size_t ws_size,
                              hipStream_t stream) {
    const float* value = (const float*)d_in[0];
    const float* key   = (const float*)d_in[1];
    const float* query = (const float*)d_in[2];
    const int*   mask  = (const int*)d_in[3];
    const float* bv = (const float*)d_in[5];
    const float* bk = (const float*)d_in[7];
    const float* bq = (const float*)d_in[9];
    const float* bo = (const float*)d_in[11];
    float* out = (float*)d_out;

    const size_t M1 = (size_t)1 << 20, M4 = (size_t)1 << 22;
    short* ws = (short*)d_ws;
    short* Xq = ws;                  // later reused as attr
    short* Xk = ws + M4;
    short* Xv = ws + 2 * M4;
    short* Wc0 = ws + 3 * M4;
    short* Wc1 = Wc0 + M1;
    short* Wc2 = Wc1 + M1;
    short* Wc3 = Wc2 + M1;
    short* qh = ws + 4 * M4;
    short* kh = ws + 5 * M4;
    short* vh = ws + 6 * M4;
    short* kt = ws + 7 * M4;
    unsigned long long* maskw = (unsigned long long*)(ws + 8 * M4);
    short* attr = Xq;

    CvtArgs cv;
    cv.src[0] = query; cv.dst[0] = Xq;
    cv.src[1] = key;   cv.dst[1] = Xk;
    cv.src[2] = value; cv.dst[2] = Xv;
    cv.src[3] = (const float*)d_in[8];  cv.dst[3] = Wc0;  // Wq
    cv.src[4] = (const float*)d_in[6];  cv.dst[4] = Wc1;  // Wk
    cv.src[5] = (const float*)d_in[4];  cv.dst[5] = Wc2;  // Wv
    cv.src[6] = (const float*)d_in[10]; cv.dst[6] = Wc3;  // Wo
    prep<<<10240, 256, 0, stream>>>(cv, mask, maskw);

    GemmArgs g1;
    g1.X[0] = Xq; g1.W[0] = Wc0; g1.B[0] = bq; g1.C[0] = qh; g1.scale[0] = QSCALE;
    g1.X[1] = Xk; g1.W[1] = Wc1; g1.B[1] = bk; g1.C[1] = kh; g1.scale[1] = 1.f;
    g1.X[2] = Xv; g1.W[2] = Wc2; g1.B[2] = bv; g1.C[2] = vh; g1.scale[2] = 1.f;
    gemm_bt<0><<<dim3(32, 8, 3), 256, 0, stream>>>(g1);

    ktr<<<dim3(32, 32), 256, 0, stream>>>(kh, kt);

    attn2<<<dim3(16, 32), 256, 0, stream>>>(qh, vh, kt, maskw, attr);

    GemmArgs g2;
    g2.X[0] = attr; g2.W[0] = Wc3; g2.B[0] = bo; g2.C[0] = out; g2.scale[0] = 1.f;
    g2.X[1] = attr; g2.W[1] = Wc3; g2.B[1] = bo; g2.C[1] = out; g2.scale[1] = 1.f;
    g2.X[2] = attr; g2.W[2] = Wc3; g2.B[2] = bo; g2.C[2] = out; g2.scale[2] = 1.f;
    gemm_bt<1><<<dim3(32, 8, 1), 256, 0, stream>>>(g2);
}

// Round 5
// 279.667 us; speedup vs baseline: 1.2173x; 1.2173x over previous
//
#include <hip/hip_runtime.h>

#define S_LEN 2048
#define DMODEL 1024
#define NHEADS 16
#define DKH 64

typedef __attribute__((ext_vector_type(8))) short bf16x8;
typedef __attribute__((ext_vector_type(4))) float f32x4;

#if __has_builtin(__builtin_amdgcn_exp2f)
#define EXP2F(x) __builtin_amdgcn_exp2f(x)
#define QSCALE (0.125f * 1.44269504f)
#else
#define EXP2F(x) __expf(x)
#define QSCALE 0.125f
#endif

static __device__ __forceinline__ short f2bf(float f) {
    unsigned b = __float_as_uint(f);
    b = (b + 0x7FFFu + ((b >> 16) & 1u)) >> 16;   // RNE
    return (short)b;
}

// pack truncated-bf16 of (lo,hi) into one u32
static __device__ __forceinline__ unsigned pktrunc(float lo, float hi) {
#if __has_builtin(__builtin_amdgcn_perm)
    return __builtin_amdgcn_perm(__float_as_uint(hi), __float_as_uint(lo), 0x07060302u);
#else
    return (__float_as_uint(lo) >> 16) | (__float_as_uint(hi) & 0xFFFF0000u);
#endif
}

static __device__ __forceinline__ f32x4 mfma16(bf16x8 a, bf16x8 b, f32x4 c) {
    return __builtin_amdgcn_mfma_f32_16x16x32_bf16(a, b, c, 0, 0, 0);
}

static __device__ __forceinline__ void glds16(const short* g, short* l) {
    __builtin_amdgcn_global_load_lds(
        (const __attribute__((address_space(1))) void*)g,
        (__attribute__((address_space(3))) void*)l, 16, 0, 0);
}

// ---------------------------------------------------------------------------
// prep: fused fp32->bf16 convert (blocks 0..8191) + mask bit-pack (2048 blocks)
// ---------------------------------------------------------------------------
struct CvtArgs { const float* src[7]; short* dst[7]; };

__global__ __launch_bounds__(256) void prep(CvtArgs a, const int* __restrict__ mask,
                                            unsigned long long* __restrict__ mw) {
    if (blockIdx.x < 8192) {
        const size_t i8 = ((size_t)blockIdx.x * 256 + threadIdx.x) * 8;
        int seg; size_t off;
        if (i8 < ((size_t)12 << 20)) { seg = (int)(i8 >> 22); off = i8 & ((1u << 22) - 1); }
        else { size_t r = i8 - ((size_t)12 << 20); seg = 3 + (int)(r >> 20); off = r & ((1u << 20) - 1); }
        const float* s = a.src[seg] + off;
        float4 x0 = *(const float4*)s, x1 = *(const float4*)(s + 4);
        short o[8];
        o[0] = f2bf(x0.x); o[1] = f2bf(x0.y); o[2] = f2bf(x0.z); o[3] = f2bf(x0.w);
        o[4] = f2bf(x1.x); o[5] = f2bf(x1.y); o[6] = f2bf(x1.z); o[7] = f2bf(x1.w);
        *(uint4*)(a.dst[seg] + off) = *(uint4*)o;
    } else {
        const int wv = ((blockIdx.x - 8192) << 2) + (threadIdx.x >> 6);
        const int lane = threadIdx.x & 63;
        const size_t base = (size_t)wv << 4;
        #pragma unroll 4
        for (int it = 0; it < 16; ++it) {
            const size_t w = base + it;
            const int m = mask[(w << 6) + lane];
            unsigned long long bal = __ballot(m != 0);
            if (lane == 0) mw[w] = bal;
        }
    }
}

// ---------------------------------------------------------------------------
// C = X @ W^T + bias (bf16, m97-style). MODE 0: bf16 headed [BH][S][DKH],
// scaled by a.scale[z]; MODE 1: fp32 flat.
// ---------------------------------------------------------------------------
struct GemmArgs { const short* X[3]; const short* W[3]; const float* B[3];
                  void* C[3]; float scale[3]; };

template <int MODE>
__global__ __launch_bounds__(256) void gemm_bt(GemmArgs a) {
    __shared__ short Ah[128 * 32];
    __shared__ short Bh[128 * 32];
    const int z = blockIdx.z;
    const short* X = a.X[z];
    const short* W = a.W[z];
    const float* bias = a.B[z];
    const float scl = a.scale[z];

    const int t = threadIdx.x, wid = t >> 6, lane = t & 63;
    const int l15 = lane & 15, lq = lane >> 4;
    const int m0 = blockIdx.x << 7, n0 = blockIdx.y << 7;
    const int wm = (wid >> 1) << 6, wn = (wid & 1) << 6;

    const int kb = (lane & 3) ^ ((lane >> 3) & 3);
    const int r0 = (wid << 5) + (lane >> 2);
    const short* ag0 = X + (size_t)(m0 + r0) * 1024 + (kb << 3);
    const short* ag1 = ag0 + 16 * 1024;
    const short* bg0 = W + (size_t)(n0 + r0) * 1024 + (kb << 3);
    const short* bg1 = bg0 + 16 * 1024;
    short* lA0 = Ah + (wid << 5) * 32;
    short* lA1 = lA0 + 16 * 32;
    short* lB0 = Bh + (wid << 5) * 32;
    short* lB1 = lB0 + 16 * 32;

    const int fpos = (lq ^ ((l15 >> 1) & 3)) << 3;

    f32x4 acc[4][4] = {};

    for (int k0 = 0; k0 < 1024; k0 += 32) {
        __syncthreads();
        glds16(ag0, lA0); glds16(ag1, lA1);
        glds16(bg0, lB0); glds16(bg1, lB1);
        ag0 += 32; ag1 += 32; bg0 += 32; bg1 += 32;
        __syncthreads();

        bf16x8 af[4], bfr[4];
        #pragma unroll
        for (int i = 0; i < 4; ++i)
            af[i] = *(const bf16x8*)&Ah[(wm + i * 16 + l15) * 32 + fpos];
        #pragma unroll
        for (int j = 0; j < 4; ++j)
            bfr[j] = *(const bf16x8*)&Bh[(wn + j * 16 + l15) * 32 + fpos];
        #pragma unroll
        for (int i = 0; i < 4; ++i)
            #pragma unroll
            for (int j = 0; j < 4; ++j)
                acc[i][j] = mfma16(af[i], bfr[j], acc[i][j]);
    }

    #pragma unroll
    for (int j = 0; j < 4; ++j) {
        const int n = n0 + wn + j * 16 + l15;
        const float bn = bias[n];
        #pragma unroll
        for (int i = 0; i < 4; ++i) {
            const int mbase = m0 + wm + i * 16 + (lq << 2);
            #pragma unroll
            for (int r = 0; r < 4; ++r) {
                const float val = (acc[i][j][r] + bn) * scl;
                const int m = mbase + r;
                if (MODE == 0) {
                    const int b = m >> 11, s = m & 2047, h = n >> 6, d = n & 63;
                    ((short*)a.C[z])[((((size_t)(b * 16 + h)) << 11) + s) * 64 + d] = f2bf(val);
                } else {
                    ((float*)a.C[z])[((size_t)m << 10) + n] = val;
                }
            }
        }
    }
}

// ---------------------------------------------------------------------------
// ktr: kh [bh][s][64] -> kt [bh][64][2048], sigma-permuted within 64-groups:
// kt[bh][d][s0+c] = kh[bh][s0 + (((c&3)<<4)|(c>>2))][d]
// ---------------------------------------------------------------------------
__global__ __launch_bounds__(256) void ktr(const short* __restrict__ kh,
                                           short* __restrict__ kt) {
    __shared__ short Ls[64 * 68];
    const int t = threadIdx.x;
    const int s0 = blockIdx.x << 6, bh = blockIdx.y;
    {
        const int r = t >> 2, cb = (t & 3) << 4;
        const short* src = kh + ((size_t)bh * 2048 + s0 + r) * 64 + cb;
        *(uint4*)&Ls[r * 68 + cb + 0] = *(const uint4*)src;
        *(uint4*)&Ls[r * 68 + cb + 8] = *(const uint4*)(src + 8);
    }
    __syncthreads();
    const int d = t >> 2, c0 = (t & 3) << 4;
    short ov[16];
    #pragma unroll
    for (int e = 0; e < 16; ++e) {
        const int c = c0 + e;
        const int jl = ((c & 3) << 4) | (c >> 2);
        ov[e] = Ls[jl * 68 + d];
    }
    short* dst = kt + ((size_t)bh * 64 + d) * 2048 + s0 + c0;
    *(uint4*)(dst + 0) = *(uint4*)(ov + 0);
    *(uint4*)(dst + 8) = *(uint4*)(ov + 8);
}

// ---------------------------------------------------------------------------
// attn3: flash attention (reference K/V swap), j-split across blockIdx.z (2
// partitions of 1024). LDS-staged V and (pre-transposed, sigma-permuted) K via
// global_load_lds; all tiles stored with XOR chunk swizzle (phys16B = logical
// ^ (row&7)) -> bank-minimum ds traffic, no padding. Fixed-max softmax,
// truncated-bf16 P (l accumulated from stored values). Outputs unnormalized
// bf16 O-partials + f32 l-partials; `combine` merges.
// Block: 4 waves x 32 q-rows = 128 rows; grid (16, 32, 2) = 4 blocks/CU.
// ---------------------------------------------------------------------------
__global__ __launch_bounds__(256, 4) void attn3(
    const short* __restrict__ Qh, const short* __restrict__ Vh,
    const short* __restrict__ Kt, const unsigned long long* __restrict__ MW,
    short* __restrict__ Opart, float* __restrict__ lpart)
{
    __shared__ short Vs[64 * 64];    // [j][d], chunk-swizzled
    __shared__ short Ks[64 * 64];    // [d][sigma(j)], chunk-swizzled
    __shared__ short Ps[128 * 64];   // [qrow][sigma(j)], chunk-swizzled

    const int t = threadIdx.x, wid = t >> 6, lane = t & 63;
    const int l15 = lane & 15, lq = lane >> 4;
    const int bh = blockIdx.y, b = bh >> 4;
    const int z = blockIdx.z;
    const int q0 = blockIdx.x << 7;
    const int rowb = q0 + (wid << 5);
    const int jbase = z << 10;

    // Q fragments (A-operand), 2 m-tiles x 2 k-panels
    bf16x8 qf[2][2];
    #pragma unroll
    for (int mt = 0; mt < 2; ++mt) {
        const short* qp = Qh + ((size_t)bh * 2048 + rowb + mt * 16 + l15) * 64 + (lq << 3);
        qf[mt][0] = *(const bf16x8*)qp;
        qf[mt][1] = *(const bf16x8*)(qp + 32);
    }

    // staging constants: wave stages 16 rows of each tile (2 glds16 per tile)
    const int sr8 = lane >> 3;               // row within 8-row group
    const int sc8 = (lane & 7) ^ sr8;        // logical chunk (xor un-swizzle)
    const int wr = wid << 4;
    const short* vsrc = Vh + (size_t)bh * 131072 + (size_t)(jbase + wr + sr8) * 64 + (sc8 << 3);
    const short* ksrc = Kt + (size_t)bh * 131072 + (size_t)(wr + sr8) * 2048 + jbase + (sc8 << 3);
    short* vdst = Vs + (wr << 6);
    short* kdst = Ks + (wr << 6);

    const unsigned long long* mwp = MW + ((size_t)b * 2048 + rowb) * 32 + (z << 4);

    // fragment-read chunk offsets (shorts), lane-constant
    const int x7 = l15 & 7;
    const int off0 = ((lq ^ x7) << 3);
    const int off1 = (((4 | lq) ^ x7) << 3);

    float rsum[2][4] = {};
    f32x4 O[2][4] = {};

    for (int jc = 0; jc < 16; ++jc) {
        __syncthreads();    // previous chunk's frag reads done
        glds16(vsrc, vdst);
        glds16(vsrc + 512, vdst + 512);
        glds16(ksrc, kdst);
        glds16(ksrc + 8 * 2048, kdst + 512);
        vsrc += 64 * 64; ksrc += 64;

        uint2 mwv[2][4];
        #pragma unroll
        for (int mt = 0; mt < 2; ++mt)
            #pragma unroll
            for (int r = 0; r < 4; ++r)
                mwv[mt][r] = *(const uint2*)(mwp + (size_t)(mt * 16 + (lq << 2) + r) * 32 + jc);
        __syncthreads();    // staging visible

        // V fragments (B-operand of QV^T): row j = nt*16+l15, k = d
        bf16x8 vf[4][2];
        #pragma unroll
        for (int nt = 0; nt < 4; ++nt) {
            const short* vp = &Vs[((nt << 4) + l15) << 6];
            vf[nt][0] = *(const bf16x8*)(vp + off0);
            vf[nt][1] = *(const bf16x8*)(vp + off1);
        }

        #pragma unroll
        for (int mt = 0; mt < 2; ++mt) {
            f32x4 sc[4];
            #pragma unroll
            for (int nt = 0; nt < 4; ++nt) {
                f32x4 c = {};
                c = mfma16(qf[mt][0], vf[nt][0], c);
                c = mfma16(qf[mt][1], vf[nt][1], c);
                sc[nt] = c;
            }
            #pragma unroll
            for (int r = 0; r < 4; ++r) {
                float p[4];
                #pragma unroll
                for (int nt = 0; nt < 4; ++nt) {
                    const unsigned sel = (nt < 2) ? mwv[mt][r].x : mwv[mt][r].y;
                    const unsigned bit = (sel >> (((nt & 1) << 4) + l15)) & 1u;
                    const float e = EXP2F(sc[nt][r]);
                    p[nt] = bit ? e : 0.f;
                }
                const unsigned u01 = pktrunc(p[0], p[1]);
                const unsigned u23 = pktrunc(p[2], p[3]);
                rsum[mt][r] += __uint_as_float(u01 << 16) + __uint_as_float(u01 & 0xFFFF0000u)
                             + __uint_as_float(u23 << 16) + __uint_as_float(u23 & 0xFFFF0000u);
                const int row7 = ((lq << 2) + r) & 7;
                const int pcw = (l15 >> 1) ^ row7;
                uint2 pw; pw.x = u01; pw.y = u23;
                *(uint2*)&Ps[(((wid << 5) + (mt << 4) + (lq << 2) + r) << 6)
                             + (pcw << 3) + ((l15 & 1) << 2)] = pw;
            }
        }

        // K fragments (B-operand of PK): row d = nt*16+l15, k = sigma(j)
        bf16x8 kf[4][2];
        #pragma unroll
        for (int nt = 0; nt < 4; ++nt) {
            const short* kp = &Ks[((nt << 4) + l15) << 6];
            kf[nt][0] = *(const bf16x8*)(kp + off0);
            kf[nt][1] = *(const bf16x8*)(kp + off1);
        }
        // P fragments (A-operand): wave-private band, same-wave lgkm dep only
        bf16x8 pf[2][2];
        #pragma unroll
        for (int mt = 0; mt < 2; ++mt) {
            const short* pp = &Ps[((wid << 5) + (mt << 4) + l15) << 6];
            pf[mt][0] = *(const bf16x8*)(pp + off0);
            pf[mt][1] = *(const bf16x8*)(pp + off1);
        }
        #pragma unroll
        for (int nt = 0; nt < 4; ++nt)
            #pragma unroll
            for (int mt = 0; mt < 2; ++mt) {
                O[mt][nt] = mfma16(pf[mt][0], kf[nt][0], O[mt][nt]);
                O[mt][nt] = mfma16(pf[mt][1], kf[nt][1], O[mt][nt]);
            }
    }

    // epilogue: partial l (16-lane reduce) + unnormalized bf16 O
    const size_t zb = (size_t)(z * 32 + bh) * 2048;
    #pragma unroll
    for (int mt = 0; mt < 2; ++mt)
        #pragma unroll
        for (int r = 0; r < 4; ++r) {
            float s = rsum[mt][r];
            #pragma unroll
            for (int d = 1; d < 16; d <<= 1)
                s += __shfl_xor(s, d, 64);
            const int row = rowb + (mt << 4) + (lq << 2) + r;
            if (l15 == 0) lpart[zb + row] = s;
            #pragma unroll
            for (int nt = 0; nt < 4; ++nt)
                Opart[(zb + row) * 64 + (nt << 4) + l15] = f2bf(O[mt][nt][r]);
        }
}

// ---------------------------------------------------------------------------
// combine: attr[b][s][h*64+d] = (O0+O1)/(l0+l1), bf16 out
// ---------------------------------------------------------------------------
__global__ __launch_bounds__(256) void combine(const short* __restrict__ Op,
                                               const float* __restrict__ lp,
                                               short* __restrict__ attr) {
    const int idx = blockIdx.x * 256 + threadIdx.x;      // 524288 total
    const int d8 = (idx & 7) << 3;
    const int srow = (idx >> 3) & 2047;
    const int bh = idx >> 14, b = bh >> 4, h = bh & 15;
    const size_t r0 = (size_t)bh * 2048 + srow;
    const size_t r1 = r0 + (size_t)32 * 2048;
    const short* p0 = Op + r0 * 64 + d8;
    const short* p1 = Op + r1 * 64 + d8;
    uint4 a = *(const uint4*)p0;
    uint4 c = *(const uint4*)p1;
    const float inv = 1.f / (lp[r0] + lp[r1]);
    const unsigned* au = (const unsigned*)&a;
    const unsigned* cu = (const unsigned*)&c;
    short o[8];
    #pragma unroll
    for (int i = 0; i < 4; ++i) {
        const float a0 = __uint_as_float(au[i] << 16);
        const float a1 = __uint_as_float(au[i] & 0xFFFF0000u);
        const float c0 = __uint_as_float(cu[i] << 16);
        const float c1 = __uint_as_float(cu[i] & 0xFFFF0000u);
        o[2 * i + 0] = f2bf((a0 + c0) * inv);
        o[2 * i + 1] = f2bf((a1 + c1) * inv);
    }
    *(uint4*)&attr[((size_t)b * 2048 + srow) * 1024 + (h << 6) + d8] = *(uint4*)o;
}

// ---------------------------------------------------------------------------
extern "C" void kernel_launch(void* const* d_in, const int* in_sizes, int n_in,
                              void* d_out, int out_size, void* d_ws, size_t ws_size,
                              hipStream_t stream) {
    const float* value = (const float*)d_in[0];
    const float* key   = (const float*)d_in[1];
    const float* query = (const float*)d_in[2];
    const int*   mask  = (const int*)d_in[3];
    const float* bv = (const float*)d_in[5];
    const float* bk = (const float*)d_in[7];
    const float* bq = (const float*)d_in[9];
    const float* bo = (const float*)d_in[11];
    float* out = (float*)d_out;

    const size_t M1 = (size_t)1 << 20, M4 = (size_t)1 << 22;
    short* ws = (short*)d_ws;
    short* Xq = ws;                       // reused as attr after proj
    short* Xk = ws + M4;                  // reused as Opart after proj
    short* Xv = ws + 2 * M4;
    short* Wc0 = ws + 3 * M4;             // reused as lpart after proj
    short* Wc1 = Wc0 + M1;
    short* Wc2 = Wc1 + M1;
    short* Wc3 = Wc2 + M1;
    short* qh = ws + 4 * M4;
    short* kh = ws + 5 * M4;
    short* vh = ws + 6 * M4;
    short* kt = ws + 7 * M4;
    unsigned long long* maskw = (unsigned long long*)(ws + 8 * M4);
    short* attr = Xq;
    short* Opart = Xk;                    // 2*32*2048*64 shorts = 2*M4 exactly
    float* lpart = (float*)Wc0;           // 131072 floats

    CvtArgs cv;
    cv.src[0] = query; cv.dst[0] = Xq;
    cv.src[1] = key;   cv.dst[1] = Xk;
    cv.src[2] = value; cv.dst[2] = Xv;
    cv.src[3] = (const float*)d_in[8];  cv.dst[3] = Wc0;  // Wq
    cv.src[4] = (const float*)d_in[6];  cv.dst[4] = Wc1;  // Wk
    cv.src[5] = (const float*)d_in[4];  cv.dst[5] = Wc2;  // Wv
    cv.src[6] = (const float*)d_in[10]; cv.dst[6] = Wc3;  // Wo
    prep<<<10240, 256, 0, stream>>>(cv, mask, maskw);

    GemmArgs g1;
    g1.X[0] = Xq; g1.W[0] = Wc0; g1.B[0] = bq; g1.C[0] = qh; g1.scale[0] = QSCALE;
    g1.X[1] = Xk; g1.W[1] = Wc1; g1.B[1] = bk; g1.C[1] = kh; g1.scale[1] = 1.f;
    g1.X[2] = Xv; g1.W[2] = Wc2; g1.B[2] = bv; g1.C[2] = vh; g1.scale[2] = 1.f;
    gemm_bt<0><<<dim3(32, 8, 3), 256, 0, stream>>>(g1);

    ktr<<<dim3(32, 32), 256, 0, stream>>>(kh, kt);

    attn3<<<dim3(16, 32, 2), 256, 0, stream>>>(qh, vh, kt, maskw, Opart, lpart);

    combine<<<2048, 256, 0, stream>>>(Opart, lpart, attr);

    GemmArgs g2;
    g2.X[0] = attr; g2.W[0] = Wc3; g2.B[0] = bo; g2.C[0] = out; g2.scale[0] = 1.f;
    g2.X[1] = attr; g2.W[1] = Wc3; g2.B[1] = bo; g2.C[1] = out; g2.scale[1] = 1.f;
    g2.X[2] = attr; g2.W[2] = Wc3; g2.B[2] = bo; g2.C[2] = out; g2.scale[2] = 1.f;
    gemm_bt<1><<<dim3(32, 8, 1), 256, 0, stream>>>(g2);
}

// Round 6
// 270.242 us; speedup vs baseline: 1.2598x; 1.0349x over previous
//
#include <hip/hip_runtime.h>

#define S_LEN 2048
#define DMODEL 1024
#define NHEADS 16
#define DKH 64

typedef __attribute__((ext_vector_type(8))) short bf16x8;
typedef __attribute__((ext_vector_type(4))) short bf16x4;
typedef __attribute__((ext_vector_type(4))) float f32x4;

#if __has_builtin(__builtin_amdgcn_exp2f)
#define EXP2F(x) __builtin_amdgcn_exp2f(x)
#define QSCALE (0.125f * 1.44269504f)
#else
#define EXP2F(x) __expf(x)
#define QSCALE 0.125f
#endif

static __device__ __forceinline__ short f2bf(float f) {
    unsigned b = __float_as_uint(f);
    b = (b + 0x7FFFu + ((b >> 16) & 1u)) >> 16;   // RNE
    return (short)b;
}

// pack truncated-bf16 of (lo,hi) into one u32
static __device__ __forceinline__ unsigned pktrunc(float lo, float hi) {
#if __has_builtin(__builtin_amdgcn_perm)
    return __builtin_amdgcn_perm(__float_as_uint(hi), __float_as_uint(lo), 0x07060302u);
#else
    return (__float_as_uint(lo) >> 16) | (__float_as_uint(hi) & 0xFFFF0000u);
#endif
}

static __device__ __forceinline__ f32x4 mfma16(bf16x8 a, bf16x8 b, f32x4 c) {
    return __builtin_amdgcn_mfma_f32_16x16x32_bf16(a, b, c, 0, 0, 0);
}

static __device__ __forceinline__ f32x4 mfma_k16(bf16x4 a, bf16x4 b, f32x4 c) {
    return __builtin_amdgcn_mfma_f32_16x16x16bf16_1k(a, b, c, 0, 0, 0);
}

static __device__ __forceinline__ void glds16(const short* g, short* l) {
    __builtin_amdgcn_global_load_lds(
        (const __attribute__((address_space(1))) void*)g,
        (__attribute__((address_space(3))) void*)l, 16, 0, 0);
}

// ---------------------------------------------------------------------------
// prep: fused fp32->bf16 convert (blocks 0..8191) + mask bit-pack (2048 blocks)
// ---------------------------------------------------------------------------
struct CvtArgs { const float* src[7]; short* dst[7]; };

__global__ __launch_bounds__(256) void prep(CvtArgs a, const int* __restrict__ mask,
                                            unsigned long long* __restrict__ mw) {
    if (blockIdx.x < 8192) {
        const size_t i8 = ((size_t)blockIdx.x * 256 + threadIdx.x) * 8;
        int seg; size_t off;
        if (i8 < ((size_t)12 << 20)) { seg = (int)(i8 >> 22); off = i8 & ((1u << 22) - 1); }
        else { size_t r = i8 - ((size_t)12 << 20); seg = 3 + (int)(r >> 20); off = r & ((1u << 20) - 1); }
        const float* s = a.src[seg] + off;
        float4 x0 = *(const float4*)s, x1 = *(const float4*)(s + 4);
        short o[8];
        o[0] = f2bf(x0.x); o[1] = f2bf(x0.y); o[2] = f2bf(x0.z); o[3] = f2bf(x0.w);
        o[4] = f2bf(x1.x); o[5] = f2bf(x1.y); o[6] = f2bf(x1.z); o[7] = f2bf(x1.w);
        *(uint4*)(a.dst[seg] + off) = *(uint4*)o;
    } else {
        const int wv = ((blockIdx.x - 8192) << 2) + (threadIdx.x >> 6);
        const int lane = threadIdx.x & 63;
        const size_t base = (size_t)wv << 4;
        #pragma unroll 4
        for (int it = 0; it < 16; ++it) {
            const size_t w = base + it;
            const int m = mask[(w << 6) + lane];
            unsigned long long bal = __ballot(m != 0);
            if (lane == 0) mw[w] = bal;
        }
    }
}

// ---------------------------------------------------------------------------
// C = X @ W^T + bias (bf16, m97-style), 128x128 tile, BK=32, glds16 staging.
// MODE 0: z<2 -> bf16 headed [BH][S][DKH] (scaled); z==2 -> TRANSPOSED headed
// kt[bh][d][s] (bias indexed by m-row = output feature, block m/n roles
// swapped so grid stays (32,8,3)). MODE 1: fp32 flat [M][N].
// ---------------------------------------------------------------------------
struct GemmArgs { const short* X[3]; const short* W[3]; const float* B[3];
                  void* C[3]; float scale[3]; };

template <int MODE>
__global__ __launch_bounds__(256) void gemm_bt(GemmArgs a) {
    __shared__ short Ah[128 * 32];
    __shared__ short Bh[128 * 32];
    const int z = blockIdx.z;
    const short* X = a.X[z];
    const short* W = a.W[z];
    const float* bias = a.B[z];
    const float scl = a.scale[z];

    const int t = threadIdx.x, wid = t >> 6, lane = t & 63;
    const int l15 = lane & 15, lq = lane >> 4;
    int m0, n0;
    if (MODE == 0 && z == 2) { m0 = blockIdx.y << 7; n0 = blockIdx.x << 7; }
    else                     { m0 = blockIdx.x << 7; n0 = blockIdx.y << 7; }
    const int wm = (wid >> 1) << 6, wn = (wid & 1) << 6;

    const int kb = (lane & 3) ^ ((lane >> 3) & 3);
    const int r0 = (wid << 5) + (lane >> 2);
    const short* ag0 = X + (size_t)(m0 + r0) * 1024 + (kb << 3);
    const short* ag1 = ag0 + 16 * 1024;
    const short* bg0 = W + (size_t)(n0 + r0) * 1024 + (kb << 3);
    const short* bg1 = bg0 + 16 * 1024;
    short* lA0 = Ah + (wid << 5) * 32;
    short* lA1 = lA0 + 16 * 32;
    short* lB0 = Bh + (wid << 5) * 32;
    short* lB1 = lB0 + 16 * 32;

    const int fpos = (lq ^ ((l15 >> 1) & 3)) << 3;

    f32x4 acc[4][4] = {};

    for (int k0 = 0; k0 < 1024; k0 += 32) {
        __syncthreads();
        glds16(ag0, lA0); glds16(ag1, lA1);
        glds16(bg0, lB0); glds16(bg1, lB1);
        ag0 += 32; ag1 += 32; bg0 += 32; bg1 += 32;
        __syncthreads();

        bf16x8 af[4], bfr[4];
        #pragma unroll
        for (int i = 0; i < 4; ++i)
            af[i] = *(const bf16x8*)&Ah[(wm + i * 16 + l15) * 32 + fpos];
        #pragma unroll
        for (int j = 0; j < 4; ++j)
            bfr[j] = *(const bf16x8*)&Bh[(wn + j * 16 + l15) * 32 + fpos];
        #pragma unroll
        for (int i = 0; i < 4; ++i)
            #pragma unroll
            for (int j = 0; j < 4; ++j)
                acc[i][j] = mfma16(af[i], bfr[j], acc[i][j]);
    }

    if (MODE == 0 && z == 2) {
        // transposed headed write: kt[(b*16+h)*64+d][s], o = m-row feature
        #pragma unroll
        for (int i = 0; i < 4; ++i) {
            #pragma unroll
            for (int r = 0; r < 4; ++r) {
                const int o = m0 + wm + i * 16 + (lq << 2) + r;
                const float bo_ = bias[o];
                const int h = o >> 6, d = o & 63;
                #pragma unroll
                for (int j = 0; j < 4; ++j) {
                    const int n = n0 + wn + j * 16 + l15;
                    const int bb = n >> 11, s = n & 2047;
                    ((short*)a.C[2])[(((size_t)((bb * 16 + h) << 6) + d) << 11) + s] =
                        f2bf(acc[i][j][r] + bo_);
                }
            }
        }
        return;
    }

    #pragma unroll
    for (int j = 0; j < 4; ++j) {
        const int n = n0 + wn + j * 16 + l15;
        const float bn = bias[n];
        #pragma unroll
        for (int i = 0; i < 4; ++i) {
            const int mbase = m0 + wm + i * 16 + (lq << 2);
            #pragma unroll
            for (int r = 0; r < 4; ++r) {
                const float val = (acc[i][j][r] + bn) * scl;
                const int m = mbase + r;
                if (MODE == 0) {
                    const int b = m >> 11, s = m & 2047, h = n >> 6, d = n & 63;
                    ((short*)a.C[z])[((((size_t)(b * 16 + h)) << 11) + s) * 64 + d] = f2bf(val);
                } else {
                    ((float*)a.C[z])[((size_t)m << 10) + n] = val;
                }
            }
        }
    }
}

// ---------------------------------------------------------------------------
// attn4: transposed-S flash attention (reference K/V swap). S^T = V@Q^T via
// 16x16x32 (C-layout col=i=l15, row=j=lq*4+r) -> exp'd scores ARE the
// A-fragments of 16x16x16 PV MFMAs (zero P LDS traffic). l via MFMA against
// all-ones B (exact sum of the truncated P fed to PV). V and kt staged in LDS
// with 16B XOR swizzle. j-split z=2; partials merged by `combine`.
// Block: 4 waves x 32 i-rows = 128 rows; grid (16, 32, 2).
// ---------------------------------------------------------------------------
__global__ __launch_bounds__(256, 4) void attn4(
    const short* __restrict__ Qh, const short* __restrict__ Vh,
    const short* __restrict__ Kt, const unsigned long long* __restrict__ MW,
    short* __restrict__ Opart, float* __restrict__ lpart)
{
    __shared__ short Vs[64 * 64];    // [j][d], 16B-chunk xor-swizzled
    __shared__ short Ks[64 * 64];    // [d][j], 16B-chunk xor-swizzled

    const int t = threadIdx.x, wid = t >> 6, lane = t & 63;
    const int l15 = lane & 15, lq = lane >> 4;
    const int bh = blockIdx.y, b = bh >> 4;
    const int z = blockIdx.z;
    const int ib = (blockIdx.x << 7) + (wid << 5);
    const int jbase = z << 10;

    // Q B-frags: B[n=i][k=d], rows ib + it*16 + l15
    bf16x8 qf[2][2];
    #pragma unroll
    for (int it = 0; it < 2; ++it) {
        const short* qp = Qh + ((size_t)bh * 2048 + ib + it * 16 + l15) * 64 + (lq << 3);
        qf[it][0] = *(const bf16x8*)qp;
        qf[it][1] = *(const bf16x8*)(qp + 32);
    }

    // staging: each wave stages 16 rows of V and 16 d-rows of Kt
    const int sr = lane >> 3, pc = lane & 7;
    const int lc = pc ^ sr;                      // logical 16B chunk
    const int wr = wid << 4;
    const short* vsrc = Vh + (size_t)bh * 131072 + (size_t)(jbase + wr + sr) * 64 + (lc << 3);
    const short* ksrc = Kt + (size_t)bh * 131072 + (size_t)(wr + sr) * 2048 + jbase + (lc << 3);
    short* vdst = Vs + (wr << 6);
    short* kdst = Ks + (wr << 6);

    const unsigned long long* mwp0 = MW + ((size_t)b * 2048 + ib + l15) * 32 + (z << 4);
    const unsigned long long* mwp1 = mwp0 + (size_t)16 * 32;

    const int x7 = l15 & 7;
    int voff[2], koff[4];
    #pragma unroll
    for (int p = 0; p < 2; ++p) voff[p] = (((p << 2) + lq) ^ x7) << 3;
    #pragma unroll
    for (int jt = 0; jt < 4; ++jt) {
        const int c8 = (jt << 2) + lq;           // logical 8B chunk
        koff[jt] = (((c8 >> 1) ^ x7) << 3) + ((c8 & 1) << 2);
    }

    f32x4 O[2][4] = {};
    f32x4 lsum[2] = {};
    bf16x4 ones;
    #pragma unroll
    for (int e = 0; e < 4; ++e) ones[e] = (short)0x3F80;

    for (int jc = 0; jc < 16; ++jc) {
        __syncthreads();
        glds16(vsrc, vdst);
        glds16(vsrc + 512, vdst + 512);
        glds16(ksrc, kdst);
        glds16(ksrc + 8 * 2048, kdst + 512);
        vsrc += 4096; ksrc += 64;

        uint2 mword[2];
        mword[0] = *(const uint2*)(mwp0 + jc);
        mword[1] = *(const uint2*)(mwp1 + jc);
        __syncthreads();

        // V A-frags: A[m=j][k=d]
        bf16x8 vf[4][2];
        #pragma unroll
        for (int jt = 0; jt < 4; ++jt) {
            const short* vp = &Vs[((jt << 4) + l15) << 6];
            vf[jt][0] = *(const bf16x8*)(vp + voff[0]);
            vf[jt][1] = *(const bf16x8*)(vp + voff[1]);
        }

        // S^T tiles -> exp -> P A-frags (registers), l via ones-MFMA
        bf16x4 paf[2][4];
        #pragma unroll
        for (int it = 0; it < 2; ++it) {
            const unsigned wx = mword[it].x, wy = mword[it].y;
            #pragma unroll
            for (int jt = 0; jt < 4; ++jt) {
                f32x4 sc = {};
                sc = mfma16(vf[jt][0], qf[it][0], sc);
                sc = mfma16(vf[jt][1], qf[it][1], sc);
                const unsigned w32 = (jt < 2) ? wx : wy;
                float p[4];
                #pragma unroll
                for (int r = 0; r < 4; ++r) {
                    const unsigned bit = (w32 >> (((jt & 1) << 4) + (lq << 2) + r)) & 1u;
                    const float e = EXP2F(sc[r]);
                    p[r] = bit ? e : 0.f;
                }
                uint2 uu;
                uu.x = pktrunc(p[0], p[1]);
                uu.y = pktrunc(p[2], p[3]);
                paf[it][jt] = __builtin_bit_cast(bf16x4, uu);
                lsum[it] = mfma_k16(paf[it][jt], ones, lsum[it]);
            }
        }

        // O += P @ K : B[n=d][k=j] from swizzled Ks, b64 reads
        #pragma unroll
        for (int dt = 0; dt < 4; ++dt) {
            const short* kp = &Ks[((dt << 4) + l15) << 6];
            #pragma unroll
            for (int jt = 0; jt < 4; ++jt) {
                const bf16x4 kfv = *(const bf16x4*)(kp + koff[jt]);
                O[0][dt] = mfma_k16(paf[0][jt], kfv, O[0][dt]);
                O[1][dt] = mfma_k16(paf[1][jt], kfv, O[1][dt]);
            }
        }
    }

    // epilogue: rows i = lq*4+r; cols d = dt*16+l15; l duplicated across l15
    const size_t zb = (size_t)((z << 5) + bh) * 2048;
    #pragma unroll
    for (int it = 0; it < 2; ++it) {
        const int rb = ib + (it << 4) + (lq << 2);
        if (l15 == 0) {
            #pragma unroll
            for (int r = 0; r < 4; ++r)
                lpart[zb + rb + r] = lsum[it][r];
        }
        #pragma unroll
        for (int dt = 0; dt < 4; ++dt)
            #pragma unroll
            for (int r = 0; r < 4; ++r)
                Opart[(zb + rb + r) * 64 + (dt << 4) + l15] = f2bf(O[it][dt][r]);
    }
}

// ---------------------------------------------------------------------------
// combine: attr[b][s][h*64+d] = (O0+O1)/(l0+l1), bf16 out
// ---------------------------------------------------------------------------
__global__ __launch_bounds__(256) void combine(const short* __restrict__ Op,
                                               const float* __restrict__ lp,
                                               short* __restrict__ attr) {
    const int idx = blockIdx.x * 256 + threadIdx.x;      // 524288 total
    const int d8 = (idx & 7) << 3;
    const int srow = (idx >> 3) & 2047;
    const int bh = idx >> 14, b = bh >> 4, h = bh & 15;
    const size_t r0 = (size_t)bh * 2048 + srow;
    const size_t r1 = r0 + (size_t)32 * 2048;
    uint4 a = *(const uint4*)(Op + r0 * 64 + d8);
    uint4 c = *(const uint4*)(Op + r1 * 64 + d8);
    const float inv = 1.f / (lp[r0] + lp[r1]);
    const unsigned* au = (const unsigned*)&a;
    const unsigned* cu = (const unsigned*)&c;
    short o[8];
    #pragma unroll
    for (int i = 0; i < 4; ++i) {
        const float a0 = __uint_as_float(au[i] << 16);
        const float a1 = __uint_as_float(au[i] & 0xFFFF0000u);
        const float c0 = __uint_as_float(cu[i] << 16);
        const float c1 = __uint_as_float(cu[i] & 0xFFFF0000u);
        o[2 * i + 0] = f2bf((a0 + c0) * inv);
        o[2 * i + 1] = f2bf((a1 + c1) * inv);
    }
    *(uint4*)&attr[((size_t)b * 2048 + srow) * 1024 + (h << 6) + d8] = *(uint4*)o;
}

// ---------------------------------------------------------------------------
extern "C" void kernel_launch(void* const* d_in, const int* in_sizes, int n_in,
                              void* d_out, int out_size, void* d_ws, size_t ws_size,
                              hipStream_t stream) {
    const float* value = (const float*)d_in[0];
    const float* key   = (const float*)d_in[1];
    const float* query = (const float*)d_in[2];
    const int*   mask  = (const int*)d_in[3];
    const float* bv = (const float*)d_in[5];
    const float* bk = (const float*)d_in[7];
    const float* bq = (const float*)d_in[9];
    const float* bo = (const float*)d_in[11];
    float* out = (float*)d_out;

    const size_t M1 = (size_t)1 << 20, M4 = (size_t)1 << 22;
    short* ws = (short*)d_ws;
    short* Xq = ws;                       // reused as attr after proj
    short* Xk = ws + M4;                  // reused as Opart after proj (2*M4)
    short* Xv = ws + 2 * M4;
    short* Wc0 = ws + 3 * M4;             // reused as lpart after proj
    short* Wc1 = Wc0 + M1;
    short* Wc2 = Wc1 + M1;
    short* Wc3 = Wc2 + M1;
    short* qh = ws + 4 * M4;
    short* kt = ws + 5 * M4;
    short* vh = ws + 6 * M4;
    unsigned long long* maskw = (unsigned long long*)(ws + 7 * M4);
    short* attr = Xq;
    short* Opart = Xk;
    float* lpart = (float*)Wc0;

    CvtArgs cv;
    cv.src[0] = query; cv.dst[0] = Xq;
    cv.src[1] = key;   cv.dst[1] = Xk;
    cv.src[2] = value; cv.dst[2] = Xv;
    cv.src[3] = (const float*)d_in[8];  cv.dst[3] = Wc0;  // Wq
    cv.src[4] = (const float*)d_in[6];  cv.dst[4] = Wc1;  // Wk
    cv.src[5] = (const float*)d_in[4];  cv.dst[5] = Wc2;  // Wv
    cv.src[6] = (const float*)d_in[10]; cv.dst[6] = Wc3;  // Wo
    prep<<<10240, 256, 0, stream>>>(cv, mask, maskw);

    GemmArgs g1;
    g1.X[0] = Xq;  g1.W[0] = Wc0; g1.B[0] = bq; g1.C[0] = qh; g1.scale[0] = QSCALE;
    g1.X[1] = Xv;  g1.W[1] = Wc2; g1.B[1] = bv; g1.C[1] = vh; g1.scale[1] = 1.f;
    g1.X[2] = Wc1; g1.W[2] = Xk;  g1.B[2] = bk; g1.C[2] = kt; g1.scale[2] = 1.f;  // transposed K
    gemm_bt<0><<<dim3(32, 8, 3), 256, 0, stream>>>(g1);

    attn4<<<dim3(16, 32, 2), 256, 0, stream>>>(qh, vh, kt, maskw, Opart, lpart);

    combine<<<2048, 256, 0, stream>>>(Opart, lpart, attr);

    GemmArgs g2;
    g2.X[0] = attr; g2.W[0] = Wc3; g2.B[0] = bo; g2.C[0] = out; g2.scale[0] = 1.f;
    g2.X[1] = attr; g2.W[1] = Wc3; g2.B[1] = bo; g2.C[1] = out; g2.scale[1] = 1.f;
    g2.X[2] = attr; g2.W[2] = Wc3; g2.B[2] = bo; g2.C[2] = out; g2.scale[2] = 1.f;
    gemm_bt<1><<<dim3(32, 8, 1), 256, 0, stream>>>(g2);
}